// Round 12
// baseline (183.514 us; speedup 1.0000x reference)
//
#include <hip/hip_runtime.h>
#include <hip/hip_cooperative_groups.h>
#include <cmath>

namespace cg = cooperative_groups;

#define BN 4096      // B*N
#define NN 64
#define GAUSS 25
#define FD 128

typedef __attribute__((ext_vector_type(8))) short bf16x8;
typedef __attribute__((ext_vector_type(4))) float f32x4;

__device__ __forceinline__ float softplus_f(float x) {
    const float t = __expf(-fabsf(x));
    return fmaxf(x, 0.f) + __logf(1.f + t);
}
__device__ __forceinline__ unsigned short f2b(float f) {
    unsigned int u = __float_as_uint(f);
    unsigned int r = (u + 0x7FFFu + ((u >> 16) & 1u)) >> 16;
    return (unsigned short)r;
}
__device__ __forceinline__ bf16x8 pack8(const float4 p0, const float4 p1) {
    bf16x8 r;
    r[0] = (short)f2b(p0.x); r[1] = (short)f2b(p0.y);
    r[2] = (short)f2b(p0.z); r[3] = (short)f2b(p0.w);
    r[4] = (short)f2b(p1.x); r[5] = (short)f2b(p1.y);
    r[6] = (short)f2b(p1.z); r[7] = (short)f2b(p1.w);
    return r;
}

// ---------------------------------------------------------------------------
// Single cooperative kernel. Grid 256 x 512 (1 block/CU, 8 waves).
//  prologue: pack wf1tA/wf2tA/wf2outB/wdenseB (global, for later phases);
//            pack win2fB into own LDS.
//  A: x = emb[z]; out[:,:128] = x; y = bf16(x) @ win2fB  (wave w: col-tile w)
//  -- grid.sync --
//  B: conv. ONE ATOM PER WAVE (2 atoms serial), barrier-free: per edge-tile
//     h1^T = wf1^T @ fij (8 MFMA) -> 4KB own-wave swizzled LDS -> W^T =
//     wf2^T @ h1^T (32 MFMA, frags streamed) fused with f32 (W+b)*C*y.
//  -- grid.sync --
//  C: out[:,128:] = softplus(agg[label] @ w_f2out + b) @ w_dense + b
// frag slot [((ks*8+ct)*64+l)*8+e] = W[k=ks*32+8*(l>>4)+e][col=ct*16+(l&15)]
// ---------------------------------------------------------------------------
__global__ __launch_bounds__(512) void fused_all(
    const float* __restrict__ emb, const int* __restrict__ zn,
    const float* __restrict__ wf1, const float* __restrict__ wf2,
    const float* __restrict__ w_in2f, const float* __restrict__ w_f2out,
    const float* __restrict__ w_dense,
    const float* __restrict__ bf1, const float* __restrict__ bf2,
    const float* __restrict__ b_f2out, const float* __restrict__ b_dense,
    const float* __restrict__ pos, const float* __restrict__ cell,
    const float* __restrict__ coff, const float* __restrict__ nmask,
    const int* __restrict__ nbr, const int* __restrict__ label,
    unsigned short* __restrict__ wf1tA, unsigned short* __restrict__ wf2tA,
    unsigned short* __restrict__ wf2outB, unsigned short* __restrict__ wdenseB,
    float* __restrict__ y, float* __restrict__ agg, float* __restrict__ out)
{
    const int t = threadIdx.x;
    const int w = t >> 6, lane = t & 63, lr = lane & 15, lg = lane >> 4;
    const int bid = blockIdx.x;

    __shared__ char smem[38912];
    unsigned short* s_w  = (unsigned short*)smem;            // A: 32KB
    float* s_r  = (float*)(smem + 32768);                    // B: 2KB [8][64]
    float* s_C  = (float*)(smem + 34816);                    // B: 2KB
    int*   s_nb = (int*)(smem + 36864);                      // B: 2KB
    unsigned short* s_t = (unsigned short*)smem;             // C: 4KB (reuse)

    // ---- prologue: pack frag arrays to global (for phases B/C) ----
    {
        const int idx = bid * 512 + t;
        if (idx < 4096) {
            const int e = idx & 7, l = (idx >> 3) & 63, ft = idx >> 9;
            const int f = ft * 16 + (l & 15);
            const int g = 8 * (l >> 4) + e;
            wf1tA[idx] = (g < GAUSS) ? f2b(wf1[g * FD + f]) : (unsigned short)0;
        } else if (idx < 20480) {
            const int i = idx - 4096;
            const int e = i & 7, l = (i >> 3) & 63, ct = (i >> 9) & 7, ks = i >> 12;
            wf2tA[i] = f2b(wf2[(ks * 32 + 8 * (l >> 4) + e) * FD + ct * 16 + (l & 15)]);
        } else if (idx < 36864) {
            const int i = idx - 20480;
            const int e = i & 7, l = (i >> 3) & 63, ct = (i >> 9) & 7, ks = i >> 12;
            wf2outB[i] = f2b(w_f2out[(ks * 32 + 8 * (l >> 4) + e) * FD + ct * 16 + (l & 15)]);
        } else if (idx < 53248) {
            const int i = idx - 36864;
            const int e = i & 7, l = (i >> 3) & 63, ct = (i >> 9) & 7, ks = i >> 12;
            wdenseB[i] = f2b(w_dense[(ks * 32 + 8 * (l >> 4) + e) * FD + ct * 16 + (l & 15)]);
        }
    }
    // ---- pack win2fB into own LDS (32 slots/thread) ----
    for (int i = t * 32, end = t * 32 + 32; i < end; ++i) {
        const int e = i & 7, l = (i >> 3) & 63, ct = (i >> 9) & 7, ks = i >> 12;
        s_w[i] = f2b(w_in2f[(ks * 32 + 8 * (l >> 4) + e) * FD + ct * 16 + (l & 15)]);
    }
    __syncthreads();

    // ---- phase A: embed + out[:, :128] + y MFMA ----
    {
        const int atom0 = bid * 16;
        const int atom = atom0 + lr;
        const int z = zn[atom];
        const float* xrow = emb + (size_t)z * FD;
        bf16x8 a[4];
#pragma unroll
        for (int ks = 0; ks < 4; ++ks) {
            const int c0 = ks * 32 + lg * 8;
            const float4 p0 = *(const float4*)&xrow[c0];
            const float4 p1 = *(const float4*)&xrow[c0 + 4];
            if (w == 0) {
                *(float4*)&out[(size_t)atom * 256 + c0] = p0;
                *(float4*)&out[(size_t)atom * 256 + c0 + 4] = p1;
            }
            a[ks] = pack8(p0, p1);
        }
        f32x4 acc = {0.f, 0.f, 0.f, 0.f};
#pragma unroll
        for (int ks = 0; ks < 4; ++ks)
            acc = __builtin_amdgcn_mfma_f32_16x16x32_bf16(
                a[ks], *(const bf16x8*)&s_w[((ks * 8 + w) * 64 + lane) * 8],
                acc, 0, 0, 0);
        const int col = w * 16 + lr;
#pragma unroll
        for (int r = 0; r < 4; ++r)
            y[(size_t)(atom0 + lg * 4 + r) * FD + col] = acc[r];
    }

    cg::this_grid().sync();

    // ---- phase B: conv, one atom per wave, 2 atoms serial ----
    {
        const float DW = 5.0f / 24.0f;
        const float CO = -0.5f / (DW * DW);
        char* h1base = smem + w * 4096;          // own-wave 4KB tile
        float* wr = s_r + w * 64;
        float* wC = s_C + w * 64;
        int*   wn = s_nb + w * 64;
        const int exor = (lr & 7) << 4;

        for (int s = 0; s < 2; ++s) {
            const int atom = bid * 16 + w + 8 * s;
            const int b = atom >> 9;

            // phase 1: distances + cutoff + ballot compaction (own wave)
            int cnt;
            {
                const int k = lane;
                const int nb = nbr[atom * NN + k];
                const float m = nmask[atom * NN + k];
                const float* cb = cell + b * 9;
                const float* co = coff + (size_t)(atom * NN + k) * 3;
                const float ox = co[0]*cb[0] + co[1]*cb[3] + co[2]*cb[6];
                const float oy = co[0]*cb[1] + co[1]*cb[4] + co[2]*cb[7];
                const float oz = co[0]*cb[2] + co[1]*cb[5] + co[2]*cb[8];
                const float* pj = pos + (size_t)((b << 9) + nb) * 3;
                const float* pi = pos + (size_t)atom * 3;
                const float dx = pj[0] + ox - pi[0];
                const float dy = pj[1] + oy - pi[1];
                const float dz = pj[2] + oz - pi[2];
                const float d2 = dx*dx + dy*dy + dz*dz;
                const float r = sqrtf(m > 0.f ? d2 : 1.0f) * m;
                const float C = (r < 5.0f) ? m : 0.f;
                const bool act = (C != 0.f);
                const unsigned long long bal = __ballot(act);
                const int pre = __popcll(bal & ((1ull << k) - 1ull));
                cnt = __popcll(bal);
                if (act) { wr[pre] = r; wC[pre] = C; wn[pre] = nb; }
                if (k >= cnt) { wr[k] = 1e20f; wC[k] = 0.f; wn[k] = 0; }
            }
            const int Rt = (cnt + 15) >> 4;

            f32x4 part[8];
#pragma unroll
            for (int j = 0; j < 8; ++j) part[j] = (f32x4){0.f, 0.f, 0.f, 0.f};

            for (int et = 0; et < Rt; ++et) {
                const int edge = et * 16 + lr;
                const float re = wr[edge];
                bf16x8 bfij;
#pragma unroll
                for (int e = 0; e < 8; ++e) {
                    const int g = 8 * lg + e;
                    float v = 0.f;
                    if (g < GAUSS) { const float d = re - (float)g * DW; v = __expf(CO * d * d); }
                    bfij[e] = (short)f2b(v);
                }
                // phase 3: h1 tile -> own LDS (swizzled rows = lr)
#pragma unroll
                for (int ct = 0; ct < 8; ++ct) {
                    const bf16x8 a1f = *(const bf16x8*)&wf1tA[(ct * 64 + lane) * 8];
                    f32x4 acc = {0.f, 0.f, 0.f, 0.f};
                    acc = __builtin_amdgcn_mfma_f32_16x16x32_bf16(a1f, bfij, acc, 0, 0, 0);
                    const float4 b1 = *(const float4*)&bf1[ct * 16 + lg * 4];
                    const unsigned int lo = (unsigned int)f2b(softplus_f(acc[0] + b1.x)) |
                                            ((unsigned int)f2b(softplus_f(acc[1] + b1.y)) << 16);
                    const unsigned int hi = (unsigned int)f2b(softplus_f(acc[2] + b1.z)) |
                                            ((unsigned int)f2b(softplus_f(acc[3] + b1.w)) << 16);
                    *(uint2*)(h1base + ((lr * 256 + (ct * 16 + lg * 4) * 2) ^ exor)) =
                        make_uint2(lo, hi);
                }
                // phase 4: W^T = wf2^T @ h1^T, fused epilogue
                bf16x8 bh[4];
#pragma unroll
                for (int hs = 0; hs < 4; ++hs)
                    bh[hs] = *(const bf16x8*)(h1base + ((lr * 256 + hs * 64 + lg * 16) ^ exor));
                const float Ce = wC[edge];
                const float* yrow = y + (size_t)((b << 9) + wn[edge]) * FD;
#pragma unroll
                for (int j = 0; j < 8; ++j) {
                    f32x4 acc = {0.f, 0.f, 0.f, 0.f};
#pragma unroll
                    for (int hs = 0; hs < 4; ++hs)
                        acc = __builtin_amdgcn_mfma_f32_16x16x32_bf16(
                            *(const bf16x8*)&wf2tA[((hs * 8 + j) * 64 + lane) * 8],
                            bh[hs], acc, 0, 0, 0);
                    const float4 yv = *(const float4*)&yrow[j * 16 + lg * 4];
                    const float4 b2 = *(const float4*)&bf2[j * 16 + lg * 4];
                    part[j][0] += (acc[0] + b2.x) * Ce * yv.x;
                    part[j][1] += (acc[1] + b2.y) * Ce * yv.y;
                    part[j][2] += (acc[2] + b2.z) * Ce * yv.z;
                    part[j][3] += (acc[3] + b2.w) * Ce * yv.w;
                }
            }
            // reduce over the 16 edge-lanes (lr) of each lg group
#pragma unroll
            for (int j = 0; j < 8; ++j) {
#pragma unroll
                for (int m = 1; m <= 8; m <<= 1) {
                    part[j][0] += __shfl_xor(part[j][0], m);
                    part[j][1] += __shfl_xor(part[j][1], m);
                    part[j][2] += __shfl_xor(part[j][2], m);
                    part[j][3] += __shfl_xor(part[j][3], m);
                }
            }
            if (lr == 0) {
#pragma unroll
                for (int j = 0; j < 8; ++j) {
                    const float4 o = {part[j][0], part[j][1], part[j][2], part[j][3]};
                    *(float4*)&agg[(size_t)atom * FD + j * 16 + lg * 4] = o;
                }
            }
        }
    }

    cg::this_grid().sync();

    // ---- phase C: out[:, 128:] = MLP(agg[label]) (gather inversion) ----
    {
        const int n0 = bid * 16;
        const int b = n0 >> 9;
        const int src = (b << 9) + label[n0 + lr];
        bf16x8 a[4];
#pragma unroll
        for (int ks = 0; ks < 4; ++ks) {
            const float* p = &agg[(size_t)src * FD + ks * 32 + lg * 8];
            a[ks] = pack8(*(const float4*)p, *(const float4*)(p + 4));
        }
        const int ct = w;
        {
            f32x4 acc = {0.f, 0.f, 0.f, 0.f};
#pragma unroll
            for (int ks = 0; ks < 4; ++ks)
                acc = __builtin_amdgcn_mfma_f32_16x16x32_bf16(
                    a[ks], *(const bf16x8*)&wf2outB[((ks * 8 + ct) * 64 + lane) * 8],
                    acc, 0, 0, 0);
            const int col = ct * 16 + lr;
            const float bias = b_f2out[col];
#pragma unroll
            for (int r = 0; r < 4; ++r) {
                const int row = lg * 4 + r;
                *(unsigned short*)((char*)s_t + ((row * 256 + col * 2) ^ ((row & 7) << 4)))
                    = f2b(softplus_f(acc[r] + bias));
            }
        }
        __syncthreads();
        bf16x8 a2[4];
#pragma unroll
        for (int ks = 0; ks < 4; ++ks)
            a2[ks] = *(const bf16x8*)((char*)s_t +
                     ((lr * 256 + (ks * 32 + lg * 8) * 2) ^ ((lr & 7) << 4)));
        {
            f32x4 acc = {0.f, 0.f, 0.f, 0.f};
#pragma unroll
            for (int ks = 0; ks < 4; ++ks)
                acc = __builtin_amdgcn_mfma_f32_16x16x32_bf16(
                    a2[ks], *(const bf16x8*)&wdenseB[((ks * 8 + ct) * 64 + lane) * 8],
                    acc, 0, 0, 0);
            const int col = ct * 16 + lr;
            const float bias = b_dense[col];
#pragma unroll
            for (int r = 0; r < 4; ++r)
                out[(size_t)(n0 + lg * 4 + r) * 256 + FD + col] = acc[r] + bias;
        }
    }
}

extern "C" void kernel_launch(void* const* d_in, const int* in_sizes, int n_in,
                              void* d_out, int out_size, void* d_ws, size_t ws_size,
                              hipStream_t stream)
{
    const float* positions = (const float*)d_in[0];
    const float* cell      = (const float*)d_in[1];
    const float* coff      = (const float*)d_in[2];
    const float* nmask     = (const float*)d_in[3];
    const float* emb       = (const float*)d_in[4];
    const float* wf1       = (const float*)d_in[5];
    const float* bf1       = (const float*)d_in[6];
    const float* wf2       = (const float*)d_in[7];
    const float* bf2       = (const float*)d_in[8];
    const float* w_in2f    = (const float*)d_in[9];
    const float* w_f2out   = (const float*)d_in[10];
    const float* b_f2out   = (const float*)d_in[11];
    const float* w_dense   = (const float*)d_in[12];
    const float* b_dense   = (const float*)d_in[13];
    const int*   zn        = (const int*)d_in[14];
    const int*   nbr       = (const int*)d_in[15];
    const int*   label     = (const int*)d_in[16];

    float* out = (float*)d_out;
    float* ws  = (float*)d_ws;
    float* y   = ws;                       // [4096,128]
    float* agg = ws + BN * FD;             // [4096,128]
    unsigned short* wf1tA   = (unsigned short*)(ws + 2 * BN * FD);  // 4096
    unsigned short* wf2tA   = wf1tA + 4096;                         // 16384
    unsigned short* wf2outB = wf2tA + 16384;                        // 16384
    unsigned short* wdenseB = wf2outB + 16384;                      // 16384

    void* args[] = {
        (void*)&emb, (void*)&zn, (void*)&wf1, (void*)&wf2, (void*)&w_in2f,
        (void*)&w_f2out, (void*)&w_dense, (void*)&bf1, (void*)&bf2,
        (void*)&b_f2out, (void*)&b_dense, (void*)&positions, (void*)&cell,
        (void*)&coff, (void*)&nmask, (void*)&nbr, (void*)&label,
        (void*)&wf1tA, (void*)&wf2tA, (void*)&wf2outB, (void*)&wdenseB,
        (void*)&y, (void*)&agg, (void*)&out
    };
    hipLaunchCooperativeKernel((const void*)fused_all, dim3(256), dim3(512),
                               args, 0, stream);
}